// Round 1
// baseline (3506.719 us; speedup 1.0000x reference)
//
#include <hip/hip_runtime.h>

typedef __attribute__((ext_vector_type(8))) short bf16x8;
typedef __attribute__((ext_vector_type(4))) float f32x4;

__device__ __forceinline__ unsigned short f2bf(float x) {
    unsigned u = __float_as_uint(x);
    u += 0x7FFFu + ((u >> 16) & 1u);
    return (unsigned short)(u >> 16);
}

__device__ __forceinline__ float sigm(float x) {
    return 1.0f / (1.0f + __expf(-x));
}

// fp32 -> bf16 cast, 4 elems/thread
__global__ __launch_bounds__(256) void k_conv_x(const float* __restrict__ src,
                                                unsigned short* __restrict__ dst, int n4) {
    int i = blockIdx.x * 256 + threadIdx.x;
    if (i >= n4) return;
    float4 v = ((const float4*)src)[i];
    ushort4 o;
    o.x = f2bf(v.x); o.y = f2bf(v.y); o.z = f2bf(v.z); o.w = f2bf(v.w);
    ((ushort4*)dst)[i] = o;
}

// Pack [Wih | Whh] -> Wcat bf16 [2048][1024]
__global__ __launch_bounds__(256) void k_conv_w(const float* __restrict__ Wih,
                                                const float* __restrict__ Whh,
                                                unsigned short* __restrict__ Wcat) {
    int i = blockIdx.x * 256 + threadIdx.x;   // float4 index over 2048*1024/4
    int k4 = (i & 255) * 4;                   // k in 0..1023, step 4
    int gc = i >> 8;                          // gate col 0..2047
    const float* s = (k4 < 512) ? (Wih + gc * 512 + k4)
                                : (Whh + gc * 512 + (k4 - 512));
    float4 v = *(const float4*)s;
    ushort4 o;
    o.x = f2bf(v.x); o.y = f2bf(v.y); o.z = f2bf(v.z); o.w = f2bf(v.w);
    ((ushort4*)Wcat)[i] = o;
}

// One LSTM timestep. Block = 4 waves; block tile = [16 rows x 16 hcols],
// wave g computes gate g's 16x16 preactivation via mfma_f32_16x16x32_bf16.
// K = 1024: k<512 from Xb[t], k>=512 from Hb[t-1]. t==0 skips h-half, c=0.
template<int FINAL>
__global__ __launch_bounds__(256)
void k_step(const unsigned short* __restrict__ Xb,  // layer input bf16 [rows][512]
            unsigned short* __restrict__ Hb,        // h history bf16 [rows][512]
            float* __restrict__ C,                  // cell state [N][512] fp32
            const unsigned short* __restrict__ Wc,  // [2048][1024] bf16
            const float* __restrict__ bih, const float* __restrict__ bhh,
            float* __restrict__ Of,                 // fp32 out (final layer only)
            int t, int N)
{
    const int tid  = threadIdx.x;
    const int lane = tid & 63;
    const int g    = tid >> 6;               // wave id == gate id (i,f,g,o)
    const int rb   = (int)blockIdx.x >> 5;   // row block (16 rows)
    const int cb   = (int)blockIdx.x & 31;   // hcol block (16 cols)
    const int gr0 = rb * 16, hc0 = cb * 16;

    __shared__ unsigned short At[16][136];   // +8 bf16 pad: rows 4 banks apart
    __shared__ float gbuf[4][16][16];

    f32x4 acc = {0.f, 0.f, 0.f, 0.f};

    const int l15 = lane & 15;
    const int lhi = lane >> 4;               // k-group 0..3

    const int srow = tid >> 4;               // staging: row 0..15
    const int skk  = (tid & 15) * 8;         // staging: k offset 0..120

    const int nch = (t == 0) ? 4 : 8;        // chunks of K=128
    for (int ch = 0; ch < nch; ++ch) {
        const int k0 = ch * 128;
        {
            const int k = k0 + skk;
            const unsigned short* src = (k < 512)
                ? Xb + (((size_t)(t * N + gr0 + srow)) << 9) + k
                : Hb + (((size_t)((t - 1) * N + gr0 + srow)) << 9) + (k - 512);
            *(float4*)&At[srow][skk] = *(const float4*)src;
        }
        __syncthreads();
        const unsigned short* wrow =
            Wc + (((size_t)(g * 512 + hc0 + l15)) << 10) + k0 + lhi * 8;
        #pragma unroll
        for (int m = 0; m < 4; ++m) {
            bf16x8 a = *(bf16x8*)&At[l15][m * 32 + lhi * 8];
            bf16x8 b = *(const bf16x8*)(wrow + m * 32);
            acc = __builtin_amdgcn_mfma_f32_16x16x32_bf16(a, b, acc, 0, 0, 0);
        }
        __syncthreads();
    }

    // C/D layout: col = lane&15, row = (lane>>4)*4 + r  [m89-verified]
    #pragma unroll
    for (int r = 0; r < 4; ++r)
        gbuf[g][lhi * 4 + r][l15] = acc[r];
    __syncthreads();

    {
        const int row  = tid >> 4;           // 0..15
        const int hc   = tid & 15;
        const int n    = gr0 + row;
        const int hcol = hc0 + hc;
        float gi = gbuf[0][row][hc] + bih[hcol]        + bhh[hcol];
        float gf = gbuf[1][row][hc] + bih[512 + hcol]  + bhh[512 + hcol];
        float gg = gbuf[2][row][hc] + bih[1024 + hcol] + bhh[1024 + hcol];
        float go = gbuf[3][row][hc] + bih[1536 + hcol] + bhh[1536 + hcol];
        float cp = (t == 0) ? 0.f : C[n * 512 + hcol];
        float cn = sigm(gf) * cp + sigm(gi) * tanhf(gg);
        float hn = sigm(go) * tanhf(cn);
        C[n * 512 + hcol] = cn;
        size_t oi = (((size_t)(t * N + n)) << 9) + hcol;
        Hb[oi] = f2bf(hn);
        if (FINAL) Of[oi] = hn;
    }
}

extern "C" void kernel_launch(void* const* d_in, const int* in_sizes, int n_in,
                              void* d_out, int out_size, void* d_ws, size_t ws_size,
                              hipStream_t stream)
{
    const float* x = (const float*)d_in[0];
    const float* Wih[3] = {(const float*)d_in[1], (const float*)d_in[5], (const float*)d_in[9]};
    const float* Whh[3] = {(const float*)d_in[2], (const float*)d_in[6], (const float*)d_in[10]};
    const float* bih[3] = {(const float*)d_in[3], (const float*)d_in[7], (const float*)d_in[11]};
    const float* bhh[3] = {(const float*)d_in[4], (const float*)d_in[8], (const float*)d_in[12]};

    char* w = (char*)d_ws;
    const size_t SZ_H = (size_t)16384 * 512;                  // activation elems
    unsigned short* Xbf = (unsigned short*)w;  w += SZ_H * 2;
    unsigned short* Hb0 = (unsigned short*)w;  w += SZ_H * 2;
    unsigned short* Hb1 = (unsigned short*)w;  w += SZ_H * 2;
    unsigned short* Hb2 = (unsigned short*)w;  w += SZ_H * 2;
    unsigned short* Wc[3];
    for (int l = 0; l < 3; ++l) { Wc[l] = (unsigned short*)w; w += (size_t)2048 * 1024 * 2; }
    float* C = (float*)w;                                     // [256][512] fp32

    // one-time (per call) conversions
    k_conv_x<<<dim3((unsigned)(SZ_H / 4 / 256)), dim3(256), 0, stream>>>(x, Xbf, (int)(SZ_H / 4));
    for (int l = 0; l < 3; ++l)
        k_conv_w<<<dim3(2048), dim3(256), 0, stream>>>(Wih[l], Whh[l], Wc[l]);

    // layer 0: Td=256, N=64  -> grid (64/16)*32 = 128
    for (int t = 0; t < 256; ++t)
        k_step<0><<<dim3(128), dim3(256), 0, stream>>>(Xbf, Hb0, C, Wc[0], bih[0], bhh[0], nullptr, t, 64);
    // layer 1: Td=128, N=128 -> grid 256
    for (int t = 0; t < 128; ++t)
        k_step<0><<<dim3(256), dim3(256), 0, stream>>>(Hb0, Hb1, C, Wc[1], bih[1], bhh[1], nullptr, t, 128);
    // layer 2: Td=64, N=256 -> grid 512, writes fp32 d_out
    for (int t = 0; t < 64; ++t)
        k_step<1><<<dim3(512), dim3(256), 0, stream>>>(Hb1, Hb2, C, Wc[2], bih[2], bhh[2], (float*)d_out, t, 256);
}